// Round 3
// baseline (576.569 us; speedup 1.0000x reference)
//
#include <hip/hip_runtime.h>
#include <math.h>

#define NB 32
#define NT 2048
#define NC 1024
#define NH 8
#define ND 128
#define TCH 16                       // t-chunks per batch; chunk = 128 rows
#define SCALE_F 0.08838834764831845f // 1/sqrt(128)

__device__ __forceinline__ float wredsum(float v) {
#pragma unroll
  for (int off = 32; off > 0; off >>= 1) v += __shfl_xor(v, off, 64);
  return v;
}

// q[i] = query_token . q_w[i,:] + q_b[i]   (one wave per output)
__global__ __launch_bounds__(256) void k_q(const float* __restrict__ qt,
                                           const float* __restrict__ q_w,
                                           const float* __restrict__ q_b,
                                           float* __restrict__ q) {
  int gw = (blockIdx.x * 256 + threadIdx.x) >> 6;
  int lane = threadIdx.x & 63;
  if (gw >= NC) return;
  const float4* a4 = (const float4*)qt;
  const float4* w4 = (const float4*)(q_w + (size_t)gw * NC);
  float acc = 0.f;
#pragma unroll
  for (int j = 0; j < 4; ++j) {
    float4 a = a4[lane + 64 * j];
    float4 w = w4[lane + 64 * j];
    acc += a.x * w.x + a.y * w.y + a.z * w.z + a.w * w.w;
  }
  acc = wredsum(acc);
  if (lane == 0) q[gw] = acc + q_b[gw];
}

// wq[h*NC+c] = sum_d q[h*ND+d]*kv_w[(h*ND+d)*NC + c];  qkb[h] = q[h,:].kv_b[h,:]
__global__ __launch_bounds__(256) void k_wq(const float* __restrict__ q,
                                            const float* __restrict__ kv_w,
                                            const float* __restrict__ kv_b,
                                            float* __restrict__ wq,
                                            float* __restrict__ qkb) {
  int tid = blockIdx.x * 256 + threadIdx.x;
  if (tid < NH * NC) {
    int h = tid >> 10;
    int c = tid & (NC - 1);
    const float* qh = q + h * ND;
    const float* w = kv_w + (size_t)(h * ND) * NC + c;
    float acc = 0.f;
#pragma unroll 4
    for (int d = 0; d < ND; ++d) acc = fmaf(qh[d], w[(size_t)d * NC], acc);
    wq[tid] = acc;
  }
  if (tid < NH) {
    const float* qh = q + tid * ND;
    const float* bb = kv_b + tid * ND;
    float acc = 0.f;
    for (int d = 0; d < ND; ++d) acc = fmaf(qh[d], bb[d], acc);
    qkb[tid] = acc;
  }
}

// Single pass over x: scores (raw -> S) + online-softmax exp-weighted x
// accumulation. Block = (b, tc): 128 rows. 4 waves x 32 rows, 2 rows/step.
// Per-wave state: m[h], l[h], acc[h][4] float4 (lane covers cols 4*(lane+64j)).
// Block-combines 4 waves in LDS, writes one partial tile + (M,L) per head.
__global__ __launch_bounds__(256, 2) void k_fused(
    const float* __restrict__ x, const int* __restrict__ mask,
    const float* __restrict__ wq, const float* __restrict__ qkb,
    float* __restrict__ S, float* __restrict__ partAcc,
    float* __restrict__ partML) {
  __shared__ float4 wq4[NH * 256];
  __shared__ float4 sacc4[NH * 256];
  __shared__ float sml[4][NH][2];
  __shared__ float qkb_s[NH];
  int tid = threadIdx.x;
  for (int i = tid; i < NH * 256; i += 256) wq4[i] = ((const float4*)wq)[i];
  if (tid < NH) qkb_s[tid] = qkb[tid];
  __syncthreads();
  int bi = blockIdx.x;
  int b = bi >> 4;
  int tc = bi & (TCH - 1);
  int w = tid >> 6, lane = tid & 63;
  int tbase = tc * 128 + w * 32;

  float m[NH], l[NH];
  float4 acc[NH][4];
#pragma unroll
  for (int h = 0; h < NH; ++h) {
    m[h] = -INFINITY;
    l[h] = 0.f;
#pragma unroll
    for (int j = 0; j < 4; ++j) acc[h][j] = make_float4(0.f, 0.f, 0.f, 0.f);
  }

  for (int step = 0; step < 16; ++step) {
    int t0 = tbase + step * 2;
    int row = b * NT + t0;
    const float4* xr = (const float4*)(x + (size_t)row * NC);
    float4 xv[2][4];
#pragma unroll
    for (int r = 0; r < 2; ++r)
#pragma unroll
      for (int j = 0; j < 4; ++j) xv[r][j] = xr[r * 256 + lane + 64 * j];
    int mk0 = mask[row];
    int mk1 = mask[row + 1];
    float bias0 = 2.0f * __expf((float)t0 * (-3.0f / 2048.0f));
    float bias1 = 2.0f * __expf((float)(t0 + 1) * (-3.0f / 2048.0f));
#pragma unroll
    for (int h = 0; h < NH; ++h) {
      float d0 = 0.f, d1 = 0.f;
#pragma unroll
      for (int j = 0; j < 4; ++j) {
        float4 wv = wq4[h * 256 + lane + 64 * j];
        d0 = fmaf(xv[0][j].x, wv.x, d0); d0 = fmaf(xv[0][j].y, wv.y, d0);
        d0 = fmaf(xv[0][j].z, wv.z, d0); d0 = fmaf(xv[0][j].w, wv.w, d0);
        d1 = fmaf(xv[1][j].x, wv.x, d1); d1 = fmaf(xv[1][j].y, wv.y, d1);
        d1 = fmaf(xv[1][j].z, wv.z, d1); d1 = fmaf(xv[1][j].w, wv.w, d1);
      }
      d0 = wredsum(d0);
      d1 = wredsum(d1);
      float v0 = mk0 ? (d0 + qkb_s[h]) * SCALE_F + bias0 : -INFINITY;
      float v1 = mk1 ? (d1 + qkb_s[h]) * SCALE_F + bias1 : -INFINITY;
      if (lane == h) {  // raw scores for attn_weights pass
        S[((size_t)(b * NH + h)) * NT + t0] = v0;
        S[((size_t)(b * NH + h)) * NT + t0 + 1] = v1;
      }
      float mnew = fmaxf(m[h], fmaxf(v0, v1));
      if (mnew > m[h]) {  // wave-uniform; exp(-inf)=0 zeroes on first hit
        float r = __expf(m[h] - mnew);
        l[h] *= r;
#pragma unroll
        for (int j = 0; j < 4; ++j) {
          acc[h][j].x *= r; acc[h][j].y *= r;
          acc[h][j].z *= r; acc[h][j].w *= r;
        }
        m[h] = mnew;
      }
      float p0 = mk0 ? __expf(v0 - m[h]) : 0.f;
      float p1 = mk1 ? __expf(v1 - m[h]) : 0.f;
      l[h] += p0 + p1;
#pragma unroll
      for (int j = 0; j < 4; ++j) {
        acc[h][j].x = fmaf(p0, xv[0][j].x, fmaf(p1, xv[1][j].x, acc[h][j].x));
        acc[h][j].y = fmaf(p0, xv[0][j].y, fmaf(p1, xv[1][j].y, acc[h][j].y));
        acc[h][j].z = fmaf(p0, xv[0][j].z, fmaf(p1, xv[1][j].z, acc[h][j].z));
        acc[h][j].w = fmaf(p0, xv[0][j].w, fmaf(p1, xv[1][j].w, acc[h][j].w));
      }
    }
  }

  // block combine across 4 waves
  if (lane == 0) {
#pragma unroll
    for (int h = 0; h < NH; ++h) {
      sml[w][h][0] = m[h];
      sml[w][h][1] = l[h];
    }
  }
  __syncthreads();
  float Mb[NH], scw[NH];
#pragma unroll
  for (int h = 0; h < NH; ++h) {
    Mb[h] = fmaxf(fmaxf(sml[0][h][0], sml[1][h][0]),
                  fmaxf(sml[2][h][0], sml[3][h][0]));
    scw[h] = (m[h] == -INFINITY) ? 0.f : __expf(m[h] - Mb[h]);
  }
  for (int ww = 0; ww < 4; ++ww) {
    if (w == ww) {
#pragma unroll
      for (int h = 0; h < NH; ++h)
#pragma unroll
        for (int j = 0; j < 4; ++j) {
          int idx = h * 256 + lane + 64 * j;
          float4 t = acc[h][j];
          t.x *= scw[h]; t.y *= scw[h]; t.z *= scw[h]; t.w *= scw[h];
          if (ww == 0) {
            sacc4[idx] = t;
          } else {
            float4 o = sacc4[idx];
            o.x += t.x; o.y += t.y; o.z += t.z; o.w += t.w;
            sacc4[idx] = o;
          }
        }
    }
    __syncthreads();
  }
  float4* pA = (float4*)(partAcc + (size_t)bi * (NH * NC));
  for (int i = tid; i < NH * 256; i += 256) pA[i] = sacc4[i];
  if (tid == 0) {
#pragma unroll
    for (int h = 0; h < NH; ++h) {
      float Lb = 0.f;
#pragma unroll
      for (int ww = 0; ww < 4; ++ww) {
        float mw = sml[ww][h][0];
        Lb += (mw == -INFINITY) ? 0.f : __expf(mw - Mb[h]) * sml[ww][h][1];
      }
      partML[(bi * NH + h) * 2] = Mb[h];
      partML[(bi * NH + h) * 2 + 1] = Lb;
    }
  }
}

// global (M, 1/L) per (b,h) from per-chunk partials. one block, 256 threads.
__global__ void k_ml(const float* __restrict__ partML, float* __restrict__ MLg) {
  int bh = threadIdx.x;
  int b = bh >> 3, h = bh & 7;
  float Mg = -INFINITY;
  for (int tc = 0; tc < TCH; ++tc)
    Mg = fmaxf(Mg, partML[((b * TCH + tc) * NH + h) * 2]);
  float Lg = 0.f;
  for (int tc = 0; tc < TCH; ++tc) {
    float mw = partML[((b * TCH + tc) * NH + h) * 2];
    if (mw != -INFINITY)
      Lg += __expf(mw - Mg) * partML[((b * TCH + tc) * NH + h) * 2 + 1];
  }
  MLg[bh * 2] = Mg;
  MLg[bh * 2 + 1] = (Lg > 0.f) ? 1.f / Lg : 0.f;
}

// xa[b,h,c] = (1/Lg) * sum_tc exp(M_tc - Mg) * partAcc[tc]
__global__ __launch_bounds__(256) void k_xared(const float* __restrict__ partAcc,
                                               const float* __restrict__ partML,
                                               const float* __restrict__ MLg,
                                               float* __restrict__ xa) {
  int tid = blockIdx.x * 256 + threadIdx.x;  // 65536 = NB*NH*256
  int bh = tid >> 8;
  int b = bh >> 3, h = bh & 7;
  int c4 = tid & 255;
  float Mg = MLg[bh * 2];
  float inv = MLg[bh * 2 + 1];
  float4 s = make_float4(0.f, 0.f, 0.f, 0.f);
  for (int tc = 0; tc < TCH; ++tc) {
    int pi = (b * TCH + tc) * NH + h;
    float mw = partML[pi * 2];
    if (mw == -INFINITY) continue;
    float scl = __expf(mw - Mg);
    float4 v = ((const float4*)partAcc)[(size_t)pi * 256 + c4];
    s.x = fmaf(scl, v.x, s.x); s.y = fmaf(scl, v.y, s.y);
    s.z = fmaf(scl, v.z, s.z); s.w = fmaf(scl, v.w, s.w);
  }
  s.x *= inv; s.y *= inv; s.z *= inv; s.w *= inv;
  ((float4*)xa)[(size_t)bh * 256 + c4] = s;
}

// attn_weights[b,t] = mean_h exp(S - Mg) / Lg
__global__ __launch_bounds__(256) void k_aw(const float* __restrict__ S,
                                            const float* __restrict__ MLg,
                                            float* __restrict__ ow) {
  int tid = blockIdx.x * 256 + threadIdx.x;  // 65536 = NB*NT
  int b = tid >> 11, t = tid & (NT - 1);
  float a = 0.f;
#pragma unroll
  for (int h = 0; h < NH; ++h) {
    float s = S[((size_t)(b * NH + h)) * NT + t];
    float Mg = MLg[(b * NH + h) * 2];
    float inv = MLg[(b * NH + h) * 2 + 1];
    a += (s == -INFINITY) ? 0.f : __expf(s - Mg) * inv;
  }
  ow[tid] = a * 0.125f;
}

// p2[b, hd] = xa[b,h,:].kv_w[NC+hd, :] + kv_b[NC+hd]  (wave per (b,hd))
__global__ __launch_bounds__(256) void k_pv(const float* __restrict__ xa,
                                            const float* __restrict__ kv_w,
                                            const float* __restrict__ kv_b,
                                            float* __restrict__ p2) {
  int gw = (blockIdx.x * 256 + threadIdx.x) >> 6;
  int lane = threadIdx.x & 63;
  if (gw >= NB * NC) return;
  int b = gw >> 10;
  int hd = gw & (NC - 1);
  int h = hd >> 7;
  const float4* a4 = (const float4*)(xa + ((size_t)(b * NH + h)) * NC);
  const float4* w4 = (const float4*)(kv_w + ((size_t)(NC + hd)) * NC);
  float acc = 0.f;
#pragma unroll
  for (int j = 0; j < 4; ++j) {
    float4 a = a4[lane + 64 * j];
    float4 w = w4[lane + 64 * j];
    acc += a.x * w.x + a.y * w.y + a.z * w.z + a.w * w.w;
  }
  acc = wredsum(acc);
  if (lane == 0) p2[(size_t)b * NC + hd] = acc + kv_b[NC + hd];
}

// out[b,i] = p2[b,:].proj_w[i,:] + proj_b[i]  (wave per (b,i))
__global__ __launch_bounds__(256) void k_proj(const float* __restrict__ p2,
                                              const float* __restrict__ proj_w,
                                              const float* __restrict__ proj_b,
                                              float* __restrict__ out) {
  int gw = (blockIdx.x * 256 + threadIdx.x) >> 6;
  int lane = threadIdx.x & 63;
  if (gw >= NB * NC) return;
  int b = gw >> 10;
  int i = gw & (NC - 1);
  const float4* a4 = (const float4*)(p2 + (size_t)b * NC);
  const float4* w4 = (const float4*)(proj_w + (size_t)i * NC);
  float acc = 0.f;
#pragma unroll
  for (int j = 0; j < 4; ++j) {
    float4 a = a4[lane + 64 * j];
    float4 w = w4[lane + 64 * j];
    acc += a.x * w.x + a.y * w.y + a.z * w.z + a.w * w.w;
  }
  acc = wredsum(acc);
  if (lane == 0) out[(size_t)b * NC + i] = acc + proj_b[i];
}

extern "C" void kernel_launch(void* const* d_in, const int* in_sizes, int n_in,
                              void* d_out, int out_size, void* d_ws, size_t ws_size,
                              hipStream_t stream) {
  const float* x = (const float*)d_in[0];
  const int* mask = (const int*)d_in[1];
  const float* qt = (const float*)d_in[2];
  const float* kv_w = (const float*)d_in[3];
  const float* kv_b = (const float*)d_in[4];
  const float* q_w = (const float*)d_in[5];
  const float* q_b = (const float*)d_in[6];
  const float* proj_w = (const float*)d_in[7];
  const float* proj_b = (const float*)d_in[8];
  float* out = (float*)d_out;

  float* ws = (float*)d_ws;
  float* q = ws;                    // 1024
  float* wq = ws + 1024;            // 8192
  float* qkb = ws + 9216;           // 8 (pad to 512)
  float* S = ws + 9728;             // NB*NH*NT = 524288
  float* partAcc = ws + 534528;     // NB*TCH*NH*NC = 4194304 (16 MiB)
  float* partML = ws + 4728832;     // NB*TCH*NH*2 = 8192
  float* MLg = ws + 4737024;        // NB*NH*2 = 512
  float* xa = ws + 4737536;         // NB*NH*NC = 262144
  float* p2 = ws + 4999680;         // NB*NC = 32768

  k_q<<<256, 256, 0, stream>>>(qt, q_w, q_b, q);
  k_wq<<<32, 256, 0, stream>>>(q, kv_w, kv_b, wq, qkb);
  k_fused<<<NB * TCH, 256, 0, stream>>>(x, mask, wq, qkb, S, partAcc, partML);
  k_ml<<<1, 256, 0, stream>>>(partML, MLg);
  k_xared<<<NB * NH, 256, 0, stream>>>(partAcc, partML, MLg, xa);
  k_aw<<<NB * NT / 256, 256, 0, stream>>>(S, MLg, out + NB * NC);
  k_pv<<<(NB * NC) / 4, 256, 0, stream>>>(xa, kv_w, kv_b, p2);
  k_proj<<<(NB * NC) / 4, 256, 0, stream>>>(p2, proj_w, proj_b, out);
}

// Round 5
// 179.342 us; speedup vs baseline: 3.2149x; 3.2149x over previous
//
#include <hip/hip_runtime.h>
#include <math.h>

#define NB 32
#define NT 2048
#define NC 1024
#define NH 8
#define ND 128
#define TCH 32                       // t-chunks per batch; chunk = 64 rows
#define SCALE_F 0.08838834764831845f // 1/sqrt(128)

__device__ __forceinline__ float wredsum(float v) {
#pragma unroll
  for (int off = 32; off > 0; off >>= 1) v += __shfl_xor(v, off, 64);
  return v;
}

// q[i] = query_token . q_w[i,:] + q_b[i]   (one wave per output)
__global__ __launch_bounds__(256) void k_q(const float* __restrict__ qt,
                                           const float* __restrict__ q_w,
                                           const float* __restrict__ q_b,
                                           float* __restrict__ q) {
  int gw = (blockIdx.x * 256 + threadIdx.x) >> 6;
  int lane = threadIdx.x & 63;
  if (gw >= NC) return;
  const float4* a4 = (const float4*)qt;
  const float4* w4 = (const float4*)(q_w + (size_t)gw * NC);
  float acc = 0.f;
#pragma unroll
  for (int j = 0; j < 4; ++j) {
    float4 a = a4[lane + 64 * j];
    float4 w = w4[lane + 64 * j];
    acc += a.x * w.x + a.y * w.y + a.z * w.z + a.w * w.w;
  }
  acc = wredsum(acc);
  if (lane == 0) q[gw] = acc + q_b[gw];
}

// wq[h*NC+c] = sum_d q[h*ND+d]*kv_w[(h*ND+d)*NC + c];  qkb[h] = q[h,:].kv_b[h,:]
__global__ __launch_bounds__(256) void k_wq(const float* __restrict__ q,
                                            const float* __restrict__ kv_w,
                                            const float* __restrict__ kv_b,
                                            float* __restrict__ wq,
                                            float* __restrict__ qkb) {
  int tid = blockIdx.x * 256 + threadIdx.x;
  if (tid < NH * NC) {
    int h = tid >> 10;
    int c = tid & (NC - 1);
    const float* qh = q + h * ND;
    const float* w = kv_w + (size_t)(h * ND) * NC + c;
    float acc = 0.f;
#pragma unroll 4
    for (int d = 0; d < ND; ++d) acc = fmaf(qh[d], w[(size_t)d * NC], acc);
    wq[tid] = acc;
  }
  if (tid < NH) {
    const float* qh = q + tid * ND;
    const float* bb = kv_b + tid * ND;
    float acc = 0.f;
    for (int d = 0; d < ND; ++d) acc = fmaf(qh[d], bb[d], acc);
    qkb[tid] = acc;
  }
}

// Single pass over x, head-split across waves: block = (b, tc) owns 64 rows;
// wave w handles heads {2w, 2w+1} over ALL 64 rows. Per-thread state:
// wq 2x16 + acc 2x16 + xv 2x16 ~ 120 VGPR -> no spills (R3 lesson).
// No LDS, no __syncthreads. Raw scores collected in regs, stored coalesced.
__global__ __launch_bounds__(256, 2) void k_fused(
    const float* __restrict__ x, const int* __restrict__ mask,
    const float* __restrict__ wq, const float* __restrict__ qkb,
    float* __restrict__ S, float* __restrict__ partAcc,
    float* __restrict__ partML) {
  int bi = blockIdx.x;  // b*TCH + tc
  int b = bi >> 5;
  int tc = bi & (TCH - 1);
  int w = threadIdx.x >> 6, lane = threadIdx.x & 63;
  int h0 = w * 2;
  int tbase = tc * 64;

  const float4* wq4 = (const float4*)wq;
  float4 wqv[2][4];
#pragma unroll
  for (int hh = 0; hh < 2; ++hh)
#pragma unroll
    for (int j = 0; j < 4; ++j)
      wqv[hh][j] = wq4[(h0 + hh) * 256 + lane + 64 * j];
  float qkbv[2] = {qkb[h0], qkb[h0 + 1]};

  float m[2] = {-INFINITY, -INFINITY};
  float l[2] = {0.f, 0.f};
  float4 acc[2][4];
#pragma unroll
  for (int hh = 0; hh < 2; ++hh)
#pragma unroll
    for (int j = 0; j < 4; ++j) acc[hh][j] = make_float4(0.f, 0.f, 0.f, 0.f);
  float sreg[2][2] = {{0.f, 0.f}, {0.f, 0.f}};  // [hh][row parity]

  const float4* xr = (const float4*)(x + (size_t)(b * NT + tbase) * NC);
  const int* mrow = mask + b * NT + tbase;

  for (int step = 0; step < 32; ++step) {
    int t0 = tbase + step * 2;
    float4 xv[2][4];
#pragma unroll
    for (int r = 0; r < 2; ++r)
#pragma unroll
      for (int j = 0; j < 4; ++j)
        xv[r][j] = xr[(step * 2 + r) * 256 + lane + 64 * j];
    int mk0 = mrow[step * 2];
    int mk1 = mrow[step * 2 + 1];
    float bias0 = 2.0f * __expf((float)t0 * (-3.0f / 2048.0f));
    float bias1 = 2.0f * __expf((float)(t0 + 1) * (-3.0f / 2048.0f));
#pragma unroll
    for (int hh = 0; hh < 2; ++hh) {
      float d0 = 0.f, d1 = 0.f;
#pragma unroll
      for (int j = 0; j < 4; ++j) {
        float4 wv = wqv[hh][j];
        d0 = fmaf(xv[0][j].x, wv.x, d0); d0 = fmaf(xv[0][j].y, wv.y, d0);
        d0 = fmaf(xv[0][j].z, wv.z, d0); d0 = fmaf(xv[0][j].w, wv.w, d0);
        d1 = fmaf(xv[1][j].x, wv.x, d1); d1 = fmaf(xv[1][j].y, wv.y, d1);
        d1 = fmaf(xv[1][j].z, wv.z, d1); d1 = fmaf(xv[1][j].w, wv.w, d1);
      }
      d0 = wredsum(d0);
      d1 = wredsum(d1);
      float v0 = mk0 ? (d0 + qkbv[hh]) * SCALE_F + bias0 : -INFINITY;
      float v1 = mk1 ? (d1 + qkbv[hh]) * SCALE_F + bias1 : -INFINITY;
      // collect raw scores: lane k (k<32) holds rows 2k (par0), 2k+1 (par1)
      sreg[hh][0] = (lane == step) ? v0 : sreg[hh][0];
      sreg[hh][1] = (lane == step) ? v1 : sreg[hh][1];
      float mnew = fmaxf(m[hh], fmaxf(v0, v1));
      if (mnew > m[hh]) {  // wave-uniform branch
        float r = __expf(m[hh] - mnew);
        l[hh] *= r;
#pragma unroll
        for (int j = 0; j < 4; ++j) {
          acc[hh][j].x *= r; acc[hh][j].y *= r;
          acc[hh][j].z *= r; acc[hh][j].w *= r;
        }
        m[hh] = mnew;
      }
      float p0 = mk0 ? __expf(v0 - m[hh]) : 0.f;
      float p1 = mk1 ? __expf(v1 - m[hh]) : 0.f;
      l[hh] += p0 + p1;
#pragma unroll
      for (int j = 0; j < 4; ++j) {
        acc[hh][j].x = fmaf(p0, xv[0][j].x, fmaf(p1, xv[1][j].x, acc[hh][j].x));
        acc[hh][j].y = fmaf(p0, xv[0][j].y, fmaf(p1, xv[1][j].y, acc[hh][j].y));
        acc[hh][j].z = fmaf(p0, xv[0][j].z, fmaf(p1, xv[1][j].z, acc[hh][j].z));
        acc[hh][j].w = fmaf(p0, xv[0][j].w, fmaf(p1, xv[1][j].w, acc[hh][j].w));
      }
    }
  }

  // coalesced raw-score store. ONLY lanes 0..31 own rows (step max = 31);
  // lanes 32..63 hold junk and writing them would stomp the next chunk (R4 bug).
  if (lane < 32) {
#pragma unroll
    for (int hh = 0; hh < 2; ++hh) {
      float2 sv = make_float2(sreg[hh][0], sreg[hh][1]);
      float2* sp = (float2*)(S + ((size_t)(b * NH + h0 + hh)) * NT + tbase);
      sp[lane] = sv;
    }
  }

  // per-wave partials: this wave fully owns heads h0, h0+1 of chunk bi
  float4* pA = (float4*)(partAcc + (size_t)bi * (NH * NC));
#pragma unroll
  for (int hh = 0; hh < 2; ++hh)
#pragma unroll
    for (int j = 0; j < 4; ++j)
      pA[(h0 + hh) * 256 + lane + 64 * j] = acc[hh][j];
  if (lane == 0) {
#pragma unroll
    for (int hh = 0; hh < 2; ++hh) {
      partML[(bi * NH + h0 + hh) * 2] = m[hh];
      partML[(bi * NH + h0 + hh) * 2 + 1] = l[hh];
    }
  }
}

// global (M, 1/L) per (b,h). one block, 256 threads (= NB*NH).
__global__ void k_ml(const float* __restrict__ partML, float* __restrict__ MLg) {
  int bh = threadIdx.x;
  int b = bh >> 3, h = bh & 7;
  float Mg = -INFINITY;
  for (int tc = 0; tc < TCH; ++tc)
    Mg = fmaxf(Mg, partML[((b * TCH + tc) * NH + h) * 2]);
  float Lg = 0.f;
  for (int tc = 0; tc < TCH; ++tc) {
    float mw = partML[((b * TCH + tc) * NH + h) * 2];
    if (mw != -INFINITY)
      Lg += __expf(mw - Mg) * partML[((b * TCH + tc) * NH + h) * 2 + 1];
  }
  MLg[bh * 2] = Mg;
  MLg[bh * 2 + 1] = (Lg > 0.f) ? 1.f / Lg : 0.f;
}

// xa[b,h,c] = (1/Lg) * sum_tc exp(M_tc - Mg) * partAcc[tc]
__global__ __launch_bounds__(256) void k_xared(const float* __restrict__ partAcc,
                                               const float* __restrict__ partML,
                                               const float* __restrict__ MLg,
                                               float* __restrict__ xa) {
  int tid = blockIdx.x * 256 + threadIdx.x;  // 65536 = NB*NH*256
  int bh = tid >> 8;
  int b = bh >> 3, h = bh & 7;
  int c4 = tid & 255;
  float Mg = MLg[bh * 2];
  float inv = MLg[bh * 2 + 1];
  float4 s = make_float4(0.f, 0.f, 0.f, 0.f);
  for (int tc = 0; tc < TCH; ++tc) {
    int pi = (b * TCH + tc) * NH + h;
    float mw = partML[pi * 2];
    if (mw == -INFINITY) continue;
    float scl = __expf(mw - Mg);
    float4 v = ((const float4*)partAcc)[(size_t)pi * 256 + c4];
    s.x = fmaf(scl, v.x, s.x); s.y = fmaf(scl, v.y, s.y);
    s.z = fmaf(scl, v.z, s.z); s.w = fmaf(scl, v.w, s.w);
  }
  s.x *= inv; s.y *= inv; s.z *= inv; s.w *= inv;
  ((float4*)xa)[(size_t)bh * 256 + c4] = s;
}

// attn_weights[b,t] = mean_h exp(S - Mg) / Lg
__global__ __launch_bounds__(256) void k_aw(const float* __restrict__ S,
                                            const float* __restrict__ MLg,
                                            float* __restrict__ ow) {
  int tid = blockIdx.x * 256 + threadIdx.x;  // 65536 = NB*NT
  int b = tid >> 11, t = tid & (NT - 1);
  float a = 0.f;
#pragma unroll
  for (int h = 0; h < NH; ++h) {
    float s = S[((size_t)(b * NH + h)) * NT + t];
    float Mg = MLg[(b * NH + h) * 2];
    float inv = MLg[(b * NH + h) * 2 + 1];
    a += (s == -INFINITY) ? 0.f : __expf(s - Mg) * inv;
  }
  ow[tid] = a * 0.125f;
}

// p2[b, hd] = xa[b,h,:].kv_w[NC+hd, :] + kv_b[NC+hd]  (wave per (b,hd))
__global__ __launch_bounds__(256) void k_pv(const float* __restrict__ xa,
                                            const float* __restrict__ kv_w,
                                            const float* __restrict__ kv_b,
                                            float* __restrict__ p2) {
  int gw = (blockIdx.x * 256 + threadIdx.x) >> 6;
  int lane = threadIdx.x & 63;
  if (gw >= NB * NC) return;
  int b = gw >> 10;
  int hd = gw & (NC - 1);
  int h = hd >> 7;
  const float4* a4 = (const float4*)(xa + ((size_t)(b * NH + h)) * NC);
  const float4* w4 = (const float4*)(kv_w + ((size_t)(NC + hd)) * NC);
  float acc = 0.f;
#pragma unroll
  for (int j = 0; j < 4; ++j) {
    float4 a = a4[lane + 64 * j];
    float4 w = w4[lane + 64 * j];
    acc += a.x * w.x + a.y * w.y + a.z * w.z + a.w * w.w;
  }
  acc = wredsum(acc);
  if (lane == 0) p2[(size_t)b * NC + hd] = acc + kv_b[NC + hd];
}

// out[b,i] = p2[b,:].proj_w[i,:] + proj_b[i]  (wave per (b,i))
__global__ __launch_bounds__(256) void k_proj(const float* __restrict__ p2,
                                              const float* __restrict__ proj_w,
                                              const float* __restrict__ proj_b,
                                              float* __restrict__ out) {
  int gw = (blockIdx.x * 256 + threadIdx.x) >> 6;
  int lane = threadIdx.x & 63;
  if (gw >= NB * NC) return;
  int b = gw >> 10;
  int i = gw & (NC - 1);
  const float4* a4 = (const float4*)(p2 + (size_t)b * NC);
  const float4* w4 = (const float4*)(proj_w + (size_t)i * NC);
  float acc = 0.f;
#pragma unroll
  for (int j = 0; j < 4; ++j) {
    float4 a = a4[lane + 64 * j];
    float4 w = w4[lane + 64 * j];
    acc += a.x * w.x + a.y * w.y + a.z * w.z + a.w * w.w;
  }
  acc = wredsum(acc);
  if (lane == 0) out[(size_t)b * NC + i] = acc + proj_b[i];
}

extern "C" void kernel_launch(void* const* d_in, const int* in_sizes, int n_in,
                              void* d_out, int out_size, void* d_ws, size_t ws_size,
                              hipStream_t stream) {
  const float* x = (const float*)d_in[0];
  const int* mask = (const int*)d_in[1];
  const float* qt = (const float*)d_in[2];
  const float* kv_w = (const float*)d_in[3];
  const float* kv_b = (const float*)d_in[4];
  const float* q_w = (const float*)d_in[5];
  const float* q_b = (const float*)d_in[6];
  const float* proj_w = (const float*)d_in[7];
  const float* proj_b = (const float*)d_in[8];
  float* out = (float*)d_out;

  float* ws = (float*)d_ws;
  float* q = ws;                    // 1024
  float* wq = ws + 1024;            // 8192
  float* qkb = ws + 9216;           // 8 (pad to 512)
  float* S = ws + 9728;             // NB*NH*NT = 524288
  float* partAcc = ws + 534528;     // NB*TCH*NH*NC = 8388608 (32 MiB)
  float* partML = ws + 8923136;     // NB*TCH*NH*2 = 16384
  float* MLg = ws + 8939520;        // NB*NH*2 = 512
  float* xa = ws + 8940032;         // NB*NH*NC = 262144
  float* p2 = ws + 9202176;         // NB*NC = 32768

  k_q<<<256, 256, 0, stream>>>(qt, q_w, q_b, q);
  k_wq<<<32, 256, 0, stream>>>(q, kv_w, kv_b, wq, qkb);
  k_fused<<<NB * TCH, 256, 0, stream>>>(x, mask, wq, qkb, S, partAcc, partML);
  k_ml<<<1, 256, 0, stream>>>(partML, MLg);
  k_xared<<<NB * NH, 256, 0, stream>>>(partAcc, partML, MLg, xa);
  k_aw<<<NB * NT / 256, 256, 0, stream>>>(S, MLg, out + NB * NC);
  k_pv<<<(NB * NC) / 4, 256, 0, stream>>>(xa, kv_w, kv_b, p2);
  k_proj<<<(NB * NC) / 4, 256, 0, stream>>>(p2, proj_w, proj_b, out);
}

// Round 6
// 139.797 us; speedup vs baseline: 4.1243x; 1.2829x over previous
//
#include <hip/hip_runtime.h>
#include <math.h>

#define NB 32
#define NT 2048
#define NC 1024
#define NH 8
#define ND 128
#define TCH 32                       // t-chunks per batch; chunk = 64 rows
#define SCALE_F 0.08838834764831845f // 1/sqrt(128)

__device__ __forceinline__ float wredsum(float v) {
#pragma unroll
  for (int off = 32; off > 0; off >>= 1) v += __shfl_xor(v, off, 64);
  return v;
}

// q[i] = query_token . q_w[i,:] + q_b[i]   (one wave per output)
__global__ __launch_bounds__(256) void k_q(const float* __restrict__ qt,
                                           const float* __restrict__ q_w,
                                           const float* __restrict__ q_b,
                                           float* __restrict__ q) {
  int gw = (blockIdx.x * 256 + threadIdx.x) >> 6;
  int lane = threadIdx.x & 63;
  if (gw >= NC) return;
  const float4* a4 = (const float4*)qt;
  const float4* w4 = (const float4*)(q_w + (size_t)gw * NC);
  float acc = 0.f;
#pragma unroll
  for (int j = 0; j < 4; ++j) {
    float4 a = a4[lane + 64 * j];
    float4 w = w4[lane + 64 * j];
    acc += a.x * w.x + a.y * w.y + a.z * w.z + a.w * w.w;
  }
  acc = wredsum(acc);
  if (lane == 0) q[gw] = acc + q_b[gw];
}

// Split-K partial wq: wqp[dq][h*NC+c] = sum_{d in [32dq,32dq+32)} q[h*128+d]*kv_w[(h*128+d)*NC+c]
// grid 32 = 8h x 4dq; 256 threads = float4 col each; coalesced b128 loads.
__global__ __launch_bounds__(256) void k_wqp(const float* __restrict__ q,
                                             const float* __restrict__ kv_w,
                                             float* __restrict__ wqp) {
  int h = blockIdx.x >> 2, dq = blockIdx.x & 3;
  int c4 = threadIdx.x;
  int dbase = h * ND + dq * 32;
  const float4* kw4 = (const float4*)kv_w;
  float4 acc = make_float4(0.f, 0.f, 0.f, 0.f);
#pragma unroll 8
  for (int dd = 0; dd < 32; ++dd) {
    float qv = q[dbase + dd];
    float4 kv = kw4[(size_t)(dbase + dd) * 256 + c4];
    acc.x = fmaf(qv, kv.x, acc.x); acc.y = fmaf(qv, kv.y, acc.y);
    acc.z = fmaf(qv, kv.z, acc.z); acc.w = fmaf(qv, kv.w, acc.w);
  }
  ((float4*)wqp)[dq * 2048 + h * 256 + c4] = acc;
}

// Single pass over x. Block = (b,tc): 64 rows. Wave w owns heads {2w,2w+1}
// over all rows (R5 layout), but x rows are staged ONCE per block in an LDS
// double buffer (2 slots x 2 rows) -> HBM reads 1x, not 4x (R5 lesson).
// Per step: prefetch next pair to regs, compute from LDS, ds_write, 1 sync.
__global__ __launch_bounds__(256, 2) void k_fused(
    const float* __restrict__ x, const int* __restrict__ mask,
    const float* __restrict__ wqp, const float* __restrict__ q,
    const float* __restrict__ kv_b,
    float* __restrict__ S, float* __restrict__ partAcc,
    float* __restrict__ partML) {
  __shared__ float xs[2][2 * NC];  // 16 KB
  int bi = blockIdx.x;  // b*TCH + tc
  int b = bi >> 5;
  int tc = bi & (TCH - 1);
  int tid = threadIdx.x;
  int w = tid >> 6, lane = tid & 63;
  int h0 = w * 2;
  int tbase = tc * 64;

  // wq fragments (sum the 4 split-K partials; L2-hot)
  const float4* wqp4 = (const float4*)wqp;
  float4 wqv[2][4];
#pragma unroll
  for (int hh = 0; hh < 2; ++hh)
#pragma unroll
    for (int j = 0; j < 4; ++j) {
      int idx = (h0 + hh) * 256 + lane + 64 * j;
      float4 s0 = wqp4[idx], s1 = wqp4[2048 + idx];
      float4 s2 = wqp4[4096 + idx], s3 = wqp4[6144 + idx];
      wqv[hh][j] = make_float4((s0.x + s1.x) + (s2.x + s3.x),
                               (s0.y + s1.y) + (s2.y + s3.y),
                               (s0.z + s1.z) + (s2.z + s3.z),
                               (s0.w + s1.w) + (s2.w + s3.w));
    }
  // qkb[h] = q[h,:].kv_b[h,:] computed in-wave (removes k_wq's second job)
  float qkbv[2];
#pragma unroll
  for (int hh = 0; hh < 2; ++hh) {
    float p = 0.f;
    if (lane < 32) {
      float4 qv = ((const float4*)(q + (h0 + hh) * ND))[lane];
      float4 bv = ((const float4*)(kv_b + (h0 + hh) * ND))[lane];
      p = qv.x * bv.x + qv.y * bv.y + qv.z * bv.z + qv.w * bv.w;
    }
    qkbv[hh] = wredsum(p);
  }

  float m[2] = {-INFINITY, -INFINITY};
  float l[2] = {0.f, 0.f};
  float4 acc[2][4];
#pragma unroll
  for (int hh = 0; hh < 2; ++hh)
#pragma unroll
    for (int j = 0; j < 4; ++j) acc[hh][j] = make_float4(0.f, 0.f, 0.f, 0.f);
  float sreg[2][2] = {{0.f, 0.f}, {0.f, 0.f}};

  const float4* x4 = (const float4*)(x + (size_t)(b * NT + tbase) * NC);
  const int* mrow = mask + b * NT + tbase;
  float4* xs4 = (float4*)xs;

  // prologue: stage rows 0,1 into slot 0
  {
    float4 s0 = x4[tid], s1 = x4[256 + tid];
    xs4[tid] = s0;
    xs4[256 + tid] = s1;
  }
  __syncthreads();

#pragma unroll 2
  for (int step = 0; step < 32; ++step) {
    int s = step & 1;
    // prefetch next row pair (HBM latency hides under compute below)
    float4 p0v, p1v;
    if (step < 31) {
      p0v = x4[(2 * step + 2) * 256 + tid];
      p1v = x4[(2 * step + 3) * 256 + tid];
    }
    int t0 = tbase + step * 2;
    float4 xv[2][4];
#pragma unroll
    for (int r = 0; r < 2; ++r)
#pragma unroll
      for (int j = 0; j < 4; ++j)
        xv[r][j] = xs4[s * 512 + r * 256 + lane + 64 * j];
    int mk0 = mrow[step * 2];
    int mk1 = mrow[step * 2 + 1];
    float bias0 = 2.0f * __expf((float)t0 * (-3.0f / 2048.0f));
    float bias1 = 2.0f * __expf((float)(t0 + 1) * (-3.0f / 2048.0f));
#pragma unroll
    for (int hh = 0; hh < 2; ++hh) {
      float d0 = 0.f, d1 = 0.f;
#pragma unroll
      for (int j = 0; j < 4; ++j) {
        float4 wv = wqv[hh][j];
        d0 = fmaf(xv[0][j].x, wv.x, d0); d0 = fmaf(xv[0][j].y, wv.y, d0);
        d0 = fmaf(xv[0][j].z, wv.z, d0); d0 = fmaf(xv[0][j].w, wv.w, d0);
        d1 = fmaf(xv[1][j].x, wv.x, d1); d1 = fmaf(xv[1][j].y, wv.y, d1);
        d1 = fmaf(xv[1][j].z, wv.z, d1); d1 = fmaf(xv[1][j].w, wv.w, d1);
      }
      d0 = wredsum(d0);
      d1 = wredsum(d1);
      float v0 = mk0 ? (d0 + qkbv[hh]) * SCALE_F + bias0 : -INFINITY;
      float v1 = mk1 ? (d1 + qkbv[hh]) * SCALE_F + bias1 : -INFINITY;
      sreg[hh][0] = (lane == step) ? v0 : sreg[hh][0];
      sreg[hh][1] = (lane == step) ? v1 : sreg[hh][1];
      float mnew = fmaxf(m[hh], fmaxf(v0, v1));
      if (mnew > m[hh]) {  // wave-uniform
        float r = __expf(m[hh] - mnew);
        l[hh] *= r;
#pragma unroll
        for (int j = 0; j < 4; ++j) {
          acc[hh][j].x *= r; acc[hh][j].y *= r;
          acc[hh][j].z *= r; acc[hh][j].w *= r;
        }
        m[hh] = mnew;
      }
      float p0 = mk0 ? __expf(v0 - m[hh]) : 0.f;
      float p1 = mk1 ? __expf(v1 - m[hh]) : 0.f;
      l[hh] += p0 + p1;
#pragma unroll
      for (int j = 0; j < 4; ++j) {
        acc[hh][j].x = fmaf(p0, xv[0][j].x, fmaf(p1, xv[1][j].x, acc[hh][j].x));
        acc[hh][j].y = fmaf(p0, xv[0][j].y, fmaf(p1, xv[1][j].y, acc[hh][j].y));
        acc[hh][j].z = fmaf(p0, xv[0][j].z, fmaf(p1, xv[1][j].z, acc[hh][j].z));
        acc[hh][j].w = fmaf(p0, xv[0][j].w, fmaf(p1, xv[1][j].w, acc[hh][j].w));
      }
    }
    // stage prefetched pair into the other slot; 1 sync/step (double buffer)
    if (step < 31) {
      xs4[(s ^ 1) * 512 + tid] = p0v;
      xs4[(s ^ 1) * 512 + 256 + tid] = p1v;
    }
    __syncthreads();
  }

  // raw-score store: ONLY lanes 0..31 own rows (R4 lesson)
  if (lane < 32) {
#pragma unroll
    for (int hh = 0; hh < 2; ++hh) {
      float2 sv = make_float2(sreg[hh][0], sreg[hh][1]);
      float2* sp = (float2*)(S + ((size_t)(b * NH + h0 + hh)) * NT + tbase);
      sp[lane] = sv;
    }
  }
  float4* pA = (float4*)(partAcc + (size_t)bi * (NH * NC));
#pragma unroll
  for (int hh = 0; hh < 2; ++hh)
#pragma unroll
    for (int j = 0; j < 4; ++j)
      pA[(h0 + hh) * 256 + lane + 64 * j] = acc[hh][j];
  if (lane == 0) {
#pragma unroll
    for (int hh = 0; hh < 2; ++hh) {
      partML[(bi * NH + h0 + hh) * 2] = m[hh];
      partML[(bi * NH + h0 + hh) * 2 + 1] = l[hh];
    }
  }
}

// Merged k_xared + k_aw (+k_ml folded in: each block recomputes its ML from
// partML, which is 64 KB and L2-hot). Blocks [0,256): xa; [256,512): attn_w.
__global__ __launch_bounds__(256) void k_xaw(const float* __restrict__ partAcc,
                                             const float* __restrict__ partML,
                                             const float* __restrict__ S,
                                             float* __restrict__ xa,
                                             float* __restrict__ ow) {
  __shared__ float Ms[NH], Is[NH];
  int blk = blockIdx.x;
  int tid = threadIdx.x;
  if (blk < NB * NH) {  // ---- xa role: one block per (b,h) ----
    int b = blk >> 3, h = blk & 7;
    float mv = -INFINITY, lv = 0.f;
    if (tid < 32) {
      mv = partML[((b * TCH + tid) * NH + h) * 2];
      lv = partML[((b * TCH + tid) * NH + h) * 2 + 1];
    }
    float Mg = mv;
#pragma unroll
    for (int off = 16; off > 0; off >>= 1) Mg = fmaxf(Mg, __shfl_xor(Mg, off, 64));
    float contrib = (tid < 32 && mv != -INFINITY) ? __expf(mv - Mg) * lv : 0.f;
#pragma unroll
    for (int off = 16; off > 0; off >>= 1) contrib += __shfl_xor(contrib, off, 64);
    if (tid == 0) {
      Ms[0] = Mg;
      Is[0] = (contrib > 0.f) ? 1.f / contrib : 0.f;
    }
    __syncthreads();
    float Mgb = Ms[0], inv = Is[0];
    float4 sacc = make_float4(0.f, 0.f, 0.f, 0.f);
    for (int tc = 0; tc < TCH; ++tc) {
      int pi = (b * TCH + tc) * NH + h;
      float mw = partML[pi * 2];
      if (mw == -INFINITY) continue;
      float scl = __expf(mw - Mgb);
      float4 v = ((const float4*)partAcc)[(size_t)pi * 256 + tid];
      sacc.x = fmaf(scl, v.x, sacc.x); sacc.y = fmaf(scl, v.y, sacc.y);
      sacc.z = fmaf(scl, v.z, sacc.z); sacc.w = fmaf(scl, v.w, sacc.w);
    }
    sacc.x *= inv; sacc.y *= inv; sacc.z *= inv; sacc.w *= inv;
    ((float4*)xa)[(size_t)blk * 256 + tid] = sacc;
  } else {  // ---- attn_weights role: one block per (b, 256-t chunk) ----
    int blkb = blk - NB * NH;
    int b = blkb >> 3, tch = blkb & 7;
    // all 8 heads' (M, 1/L): thread (h=tid>>5, tc=tid&31)
    float mv = partML[((b * TCH + (tid & 31)) * NH + (tid >> 5)) * 2];
    float lv = partML[((b * TCH + (tid & 31)) * NH + (tid >> 5)) * 2 + 1];
    float Mg = mv;
#pragma unroll
    for (int off = 16; off > 0; off >>= 1) Mg = fmaxf(Mg, __shfl_xor(Mg, off, 64));
    float contrib = (mv != -INFINITY) ? __expf(mv - Mg) * lv : 0.f;
#pragma unroll
    for (int off = 16; off > 0; off >>= 1) contrib += __shfl_xor(contrib, off, 64);
    if ((tid & 31) == 0) {
      Ms[tid >> 5] = Mg;
      Is[tid >> 5] = (contrib > 0.f) ? 1.f / contrib : 0.f;
    }
    __syncthreads();
    int t = tch * 256 + tid;
    float a = 0.f;
#pragma unroll
    for (int h = 0; h < NH; ++h) {
      float s = S[((size_t)(b * NH + h)) * NT + t];
      a += (s == -INFINITY) ? 0.f : __expf(s - Ms[h]) * Is[h];
    }
    ow[(size_t)b * NT + t] = a * 0.125f;
  }
}

// p2[b, hd] = xa[b,h,:].kv_w[NC+hd, :] + kv_b[NC+hd]  (wave per (b,hd))
__global__ __launch_bounds__(256) void k_pv(const float* __restrict__ xa,
                                            const float* __restrict__ kv_w,
                                            const float* __restrict__ kv_b,
                                            float* __restrict__ p2) {
  int gw = (blockIdx.x * 256 + threadIdx.x) >> 6;
  int lane = threadIdx.x & 63;
  if (gw >= NB * NC) return;
  int b = gw >> 10;
  int hd = gw & (NC - 1);
  int h = hd >> 7;
  const float4* a4 = (const float4*)(xa + ((size_t)(b * NH + h)) * NC);
  const float4* w4 = (const float4*)(kv_w + ((size_t)(NC + hd)) * NC);
  float acc = 0.f;
#pragma unroll
  for (int j = 0; j < 4; ++j) {
    float4 a = a4[lane + 64 * j];
    float4 w = w4[lane + 64 * j];
    acc += a.x * w.x + a.y * w.y + a.z * w.z + a.w * w.w;
  }
  acc = wredsum(acc);
  if (lane == 0) p2[(size_t)b * NC + hd] = acc + kv_b[NC + hd];
}

// out[b,i] = p2[b,:].proj_w[i,:] + proj_b[i]  (wave per (b,i))
__global__ __launch_bounds__(256) void k_proj(const float* __restrict__ p2,
                                              const float* __restrict__ proj_w,
                                              const float* __restrict__ proj_b,
                                              float* __restrict__ out) {
  int gw = (blockIdx.x * 256 + threadIdx.x) >> 6;
  int lane = threadIdx.x & 63;
  if (gw >= NB * NC) return;
  int b = gw >> 10;
  int i = gw & (NC - 1);
  const float4* a4 = (const float4*)(p2 + (size_t)b * NC);
  const float4* w4 = (const float4*)(proj_w + (size_t)i * NC);
  float acc = 0.f;
#pragma unroll
  for (int j = 0; j < 4; ++j) {
    float4 a = a4[lane + 64 * j];
    float4 w = w4[lane + 64 * j];
    acc += a.x * w.x + a.y * w.y + a.z * w.z + a.w * w.w;
  }
  acc = wredsum(acc);
  if (lane == 0) out[(size_t)b * NC + i] = acc + proj_b[i];
}

extern "C" void kernel_launch(void* const* d_in, const int* in_sizes, int n_in,
                              void* d_out, int out_size, void* d_ws, size_t ws_size,
                              hipStream_t stream) {
  const float* x = (const float*)d_in[0];
  const int* mask = (const int*)d_in[1];
  const float* qt = (const float*)d_in[2];
  const float* kv_w = (const float*)d_in[3];
  const float* kv_b = (const float*)d_in[4];
  const float* q_w = (const float*)d_in[5];
  const float* q_b = (const float*)d_in[6];
  const float* proj_w = (const float*)d_in[7];
  const float* proj_b = (const float*)d_in[8];
  float* out = (float*)d_out;

  float* ws = (float*)d_ws;
  float* q = ws;                    // 1024
  float* wqp = ws + 1024;           // 4*8192 = 32768
  float* S = ws + 33792;            // 524288
  float* partAcc = ws + 558080;     // NB*TCH*NH*NC = 8388608 (32 MiB)
  float* partML = ws + 8946688;     // 16384
  float* xa = ws + 8963072;         // 262144
  float* p2 = ws + 9225216;         // 32768

  k_q<<<256, 256, 0, stream>>>(qt, q_w, q_b, q);
  k_wqp<<<32, 256, 0, stream>>>(q, kv_w, wqp);
  k_fused<<<NB * TCH, 256, 0, stream>>>(x, mask, wqp, q, kv_b, S, partAcc, partML);
  k_xaw<<<512, 256, 0, stream>>>(partAcc, partML, S, xa, out + NB * NC);
  k_pv<<<(NB * NC) / 4, 256, 0, stream>>>(xa, kv_w, kv_b, p2);
  k_proj<<<(NB * NC) / 4, 256, 0, stream>>>(p2, proj_w, proj_b, out);
}